// Round 13
// baseline (433.774 us; speedup 1.0000x reference)
//
#include <hip/hip_runtime.h>
#include <hip/hip_bf16.h>

#define N_NODES 50000
#define N_EDGES 800000
#define N_GRAPHS 512

typedef __attribute__((ext_vector_type(8))) short short8v;   // 8 bf16
typedef __attribute__((ext_vector_type(4))) float f32x4;

__device__ inline float bf2f(unsigned short u) {
    union { unsigned int i; float f; } v; v.i = ((unsigned int)u) << 16; return v.f;
}
__device__ inline short f2bf(float f) {
    __hip_bfloat16 h = __float2bfloat16(f);
    return *reinterpret_cast<short*>(&h);
}

// ---------------------------------------------------------------------------
// PERMUTED bf16 row layout (row of D dims, D%32==0):
//   memory position m = 32*p + 2*c + half  <->  dim d = 32*p + 16*half + c
// uint i of a row = dims (32*(i>>4) + (i&15), 32*(i>>4) + 16 + (i&15))
// ---------------------------------------------------------------------------

// ======================= CSR prep =======================
__global__ __launch_bounds__(256) void count_deg(
    const int* __restrict__ dst, int* __restrict__ deg)
{
    int e = blockIdx.x * blockDim.x + threadIdx.x;
    if (e < N_EDGES) atomicAdd(&deg[dst[e]], 1);
}

__global__ __launch_bounds__(256) void assign_base(
    const int* __restrict__ deg, int* __restrict__ basep, int* __restrict__ counter)
{
    int n = blockIdx.x * blockDim.x + threadIdx.x;
    if (n < N_NODES) basep[n] = atomicAdd(counter, deg[n]);
}

// scatter edges into dst-contiguous stream: srcdst (ushort) + eadst (bf16 row)
__global__ __launch_bounds__(256) void scatter_edges(
    const int* __restrict__ dst, const int* __restrict__ src,
    const float* __restrict__ ea,
    const int* __restrict__ basep, int* __restrict__ fill,
    unsigned short* __restrict__ srcdst, unsigned short* __restrict__ eadst)
{
    int e = blockIdx.x * blockDim.x + threadIdx.x;
    if (e < N_EDGES) {
        const int d = dst[e];
        const int slot = atomicAdd(&fill[d], 1);
        const size_t pos = (size_t)basep[d] + slot;
        srcdst[pos] = (unsigned short)src[e];
        const float4* ap = (const float4*)(ea + (size_t)e * 16);
        const float4 a0 = ap[0], a1 = ap[1], a2 = ap[2], a3 = ap[3];
        short8v o0, o1;
        o0[0] = f2bf(a0.x); o0[1] = f2bf(a0.y); o0[2] = f2bf(a0.z); o0[3] = f2bf(a0.w);
        o0[4] = f2bf(a1.x); o0[5] = f2bf(a1.y); o0[6] = f2bf(a1.z); o0[7] = f2bf(a1.w);
        o1[0] = f2bf(a2.x); o1[1] = f2bf(a2.y); o1[2] = f2bf(a2.z); o1[3] = f2bf(a2.w);
        o1[4] = f2bf(a3.x); o1[5] = f2bf(a3.y); o1[6] = f2bf(a3.z); o1[7] = f2bf(a3.w);
        ((short8v*)eadst)[2 * pos]     = o0;
        ((short8v*)eadst)[2 * pos + 1] = o1;
    }
}

// ======================= merged conversions + zeroing (1 dispatch) =======================
// [0, T0): x fp32->permuted bf16 | W1aT | W1bT | W2aT | W2bT | deg=0 | fill=0 | counter=0
#define T0_CVT (N_NODES * 48)
#define TW_CVT (128 * 96 + 3 * 16384)
__global__ __launch_bounds__(256) void prep_convert(
    const float* __restrict__ x,
    const float* __restrict__ W1a, const float* __restrict__ W1b,
    const float* __restrict__ W2a, const float* __restrict__ W2b,
    unsigned int* __restrict__ x16,
    unsigned short* __restrict__ W1aT, unsigned short* __restrict__ W1bT,
    unsigned short* __restrict__ W2aT, unsigned short* __restrict__ W2bT,
    int* __restrict__ deg, int* __restrict__ fillp, int* __restrict__ counter)
{
    int t = blockIdx.x * blockDim.x + threadIdx.x;
    if (t < T0_CVT) {
        const int m2 = t % 48;
        const int n  = t / 48;
        const int p  = m2 >> 4;
        const int c  = m2 & 15;
        const float lo = x[(size_t)n * 96 + 32 * p + c];
        const float hi = x[(size_t)n * 96 + 32 * p + 16 + c];
        x16[t] = (unsigned int)(unsigned short)f2bf(lo) |
                 ((unsigned int)(unsigned short)f2bf(hi) << 16);
        return;
    }
    int u = t - T0_CVT;
    if (u < 128 * 96) { W1aT[u] = (unsigned short)f2bf(W1a[(u % 96) * 128 + u / 96]); return; }
    u -= 128 * 96;
    if (u < 16384) { W1bT[u] = (unsigned short)f2bf(W1b[(u & 127) * 128 + (u >> 7)]); return; }
    u -= 16384;
    if (u < 16384) { W2aT[u] = (unsigned short)f2bf(W2a[(u & 127) * 128 + (u >> 7)]); return; }
    u -= 16384;
    if (u < 16384) { W2bT[u] = (unsigned short)f2bf(W2b[(u & 127) * 128 + (u >> 7)]); return; }
    u -= 16384;
    if (u < N_NODES) { deg[u] = 0; return; }
    u -= N_NODES;
    if (u < N_NODES) { fillp[u] = 0; return; }
    u -= N_NODES;
    if (u == 0) { *counter = 0; }
}

// ======================= gather v9b (pipelined; UNIFORM shfl fix) =======================
template <int DIN>
__global__ __launch_bounds__(256, 8) void gather_v9(
    const unsigned short* __restrict__ hin,    // [N,DIN] bf16 permuted
    const unsigned short* __restrict__ srcdst, // [E] ushort
    const unsigned short* __restrict__ eadst,  // [E][16] bf16, dst-contiguous
    const int* __restrict__ deg,
    const int* __restrict__ basep,
    const float* __restrict__ We,              // [16,DIN] fp32
    const float* __restrict__ be,              // [DIN]
    unsigned short* __restrict__ hpre,         // [N,DIN] bf16 permuted out
    float* __restrict__ pooled_zero)           // optional: zero before mlp2
{
    constexpr int NB = DIN / 16;
    constexpr int NP = DIN / 32;

    // fold pooled zeroing into this dispatch (runs strictly before mlp MODE 1)
    if (pooled_zero) {
        const int t = blockIdx.x * blockDim.x + threadIdx.x;
        if (t < N_GRAPHS * 128 / 4) {
            ((float4*)pooled_zero)[t] = make_float4(0.f, 0.f, 0.f, 0.f);
        }
    }

    const int lane = threadIdx.x & 63;
    const int col = lane & 15;
    const int grp = lane >> 4;
    const int gwave = (blockIdx.x * blockDim.x + threadIdx.x) >> 6;
    const int nwaves = (gridDim.x * blockDim.x) >> 6;

    // B fragments: We rows k=grp*8+j (grp<2); bias row at k=16 (grp2, j=0)
    short8v Bf[NB];
#pragma unroll
    for (int b = 0; b < NB; ++b) {
        short8v f = {};
        if (grp < 2) {
#pragma unroll
            for (int j = 0; j < 8; ++j)
                f[j] = f2bf(We[(grp * 8 + j) * DIN + b * 16 + col]);
        } else if (grp == 2) {
            f[0] = f2bf(be[b * 16 + col]);
        }
        Bf[b] = f;
    }

    // contiguous node range per wave: deg/basep of consecutive nodes share lines
    const int K = (N_NODES + nwaves - 1) / nwaves;
    const int n_beg = gwave * K;
    if (n_beg >= N_NODES) return;
    const int n_end = min(n_beg + K, N_NODES);

    int dg_n = deg[n_beg];
    int bp_n = basep[n_beg];

    for (int n = n_beg; n < n_end; ++n) {
        // prefetch next node's metadata (independent of this node's work)
        int dg_nx = 0, bp_nx = 0;
        if (n + 1 < n_end) { dg_nx = deg[n + 1]; bp_nx = basep[n + 1]; }

        // early self-row load: one full-wave read, redistributed at store time
        unsigned int selfu = 0;
        if (lane < DIN / 2)
            selfu = ((const unsigned int*)(hin + (size_t)n * DIN))[lane];

        const int dgc = dg_n;
        const int b0  = bp_n;
        const int nch = (dgc + 15) >> 4;

        float accv[NB];
#pragma unroll
        for (int b = 0; b < NB; ++b) accv[b] = 0.0f;

        // chunk pipeline: statically-named cur/nxt slots
        int s_cur = 0;
        short8v ea_cur = {};
        if (nch > 0) {
            const int vcc0 = min(dgc, 16);
            if (lane < vcc0) s_cur = srcdst[b0 + lane];
            if (grp < 2) {
                if (col < vcc0)
                    ea_cur = *(const short8v*)(eadst + (size_t)(b0 + col) * 16 + grp * 8);
            } else if (grp == 2) {
                ea_cur[0] = (short)0x3F80;   // bf16 1.0 -> bias row
            }
        }

        for (int c = 0; c < nch; ++c) {
            const int vcc = min(dgc - 16 * c, 16);

            // issue next chunk's loads before consuming current
            int s_nxt = 0;
            short8v ea_nxt = {};
            if (c + 1 < nch) {
                const int vccn = min(dgc - 16 * (c + 1), 16);
                const int posn = b0 + 16 * (c + 1);
                if (lane < vccn) s_nxt = srcdst[posn + lane];
                if (grp < 2) {
                    if (col < vccn)
                        ea_nxt = *(const short8v*)(eadst + (size_t)(posn + col) * 16 + grp * 8);
                } else if (grp == 2) {
                    ea_nxt[0] = (short)0x3F80;
                }
            }

            int sid[4];
#pragma unroll
            for (int r = 0; r < 4; ++r) sid[r] = __shfl(s_cur, 4 * grp + r);

#pragma unroll
            for (int p = 0; p < NP; ++p) {
                const f32x4 zero = {0.0f, 0.0f, 0.0f, 0.0f};
                f32x4 lin0 = __builtin_amdgcn_mfma_f32_16x16x32_bf16(ea_cur, Bf[2 * p], zero, 0, 0, 0);
                f32x4 lin1 = __builtin_amdgcn_mfma_f32_16x16x32_bf16(ea_cur, Bf[2 * p + 1], zero, 0, 0, 0);
                float part0 = 0.0f, part1 = 0.0f;
#pragma unroll
                for (int r = 0; r < 4; ++r) {
                    if (4 * grp + r < vcc) {
                        const unsigned int u = *(const unsigned int*)
                            (hin + (size_t)sid[r] * DIN + 32 * p + 2 * col);
                        const float xlo = bf2f((unsigned short)(u & 0xffffu));
                        const float xhi = bf2f((unsigned short)(u >> 16));
                        part0 += fmaxf(xlo + lin0[r], 0.0f);
                        part1 += fmaxf(xhi + lin1[r], 0.0f);
                    }
                }
                accv[2 * p]     += part0;
                accv[2 * p + 1] += part1;
            }

            s_cur = s_nxt;
            ea_cur = ea_nxt;
        }

        // cross-lane reduce once per node
#pragma unroll
        for (int b = 0; b < NB; ++b) {
            accv[b] += __shfl_xor(accv[b], 16);
            accv[b] += __shfl_xor(accv[b], 32);
        }

        // redistribute self row UNIFORMLY (all 64 lanes execute the shfl;
        // ds_bpermute returns 0 from exec-inactive source lanes, so this
        // must NOT sit inside the lane<16 branch — round-12 bug).
        unsigned int up[NP];
#pragma unroll
        for (int p = 0; p < NP; ++p)
            up[p] = __shfl(selfu, 16 * p + (lane & 15));

        // self term + store (v7-style per-p 16-lane stores)
        if (lane < 16) {
#pragma unroll
            for (int p = 0; p < NP; ++p) {
                const float lo = bf2f((unsigned short)(up[p] & 0xffffu)) + accv[2 * p];
                const float hi = bf2f((unsigned short)(up[p] >> 16)) + accv[2 * p + 1];
                *(unsigned int*)(hpre + (size_t)n * DIN + 32 * p + 2 * lane) =
                    (unsigned int)(unsigned short)f2bf(lo) |
                    ((unsigned int)(unsigned short)f2bf(hi) << 16);
            }
        }

        dg_n = dg_nx;
        bp_n = bp_nx;
    }
}

// ======================= MFMA GIN MLP (proven) =======================
template <int DIN, int MODE>
__global__ __launch_bounds__(256) void mlp_mfma(
    const unsigned short* __restrict__ hpre,  // [N,DIN] bf16 permuted
    const unsigned short* __restrict__ WaT,   // [128][DIN] bf16
    const float* __restrict__ ba,
    const unsigned short* __restrict__ WbT,   // [128][128] bf16
    const float* __restrict__ bb,
    unsigned short* __restrict__ h1out,       // MODE 0 (permuted)
    const int* __restrict__ batch,            // MODE 1
    float* __restrict__ pooled)               // MODE 1 (pre-zeroed)
{
    constexpr int KS1 = DIN / 32;
    __shared__ unsigned short hls[32][DIN + 8];
    __shared__ unsigned short uls[32][128 + 8];
    __shared__ float vls[(MODE == 1) ? 32 : 1][(MODE == 1) ? 132 : 1];

    const int n0 = blockIdx.x * 32;
    const int tid = threadIdx.x;

    for (int f = tid * 4; f < 32 * DIN; f += 1024) {
        const int row = f / DIN, colc = f % DIN;
        const int n = n0 + row;
        ushort4 u = make_ushort4(0, 0, 0, 0);
        if (n < N_NODES) u = *(const ushort4*)(hpre + (size_t)n * DIN + colc);
        const int p = colc >> 5;
        const int q = (colc & 31) >> 2;
        hls[row][32 * p + 2 * q]          = u.x;
        hls[row][32 * p + 16 + 2 * q]     = u.y;
        hls[row][32 * p + 2 * q + 1]      = u.z;
        hls[row][32 * p + 16 + 2 * q + 1] = u.w;
    }
    __syncthreads();

    const int lane = tid & 63;
    const int w = tid >> 6;
    const int col = lane & 15;
    const int grp = lane >> 4;

    f32x4 acc00 = {0,0,0,0}, acc01 = {0,0,0,0}, acc10 = {0,0,0,0}, acc11 = {0,0,0,0};
#pragma unroll
    for (int ks = 0; ks < KS1; ++ks) {
        const short8v A0 = *(const short8v*)&hls[col][ks * 32 + grp * 8];
        const short8v A1 = *(const short8v*)&hls[16 + col][ks * 32 + grp * 8];
        const short8v B0 = *(const short8v*)&WaT[(size_t)(2 * w * 16 + col) * DIN + ks * 32 + grp * 8];
        const short8v B1 = *(const short8v*)&WaT[(size_t)((2 * w + 1) * 16 + col) * DIN + ks * 32 + grp * 8];
        acc00 = __builtin_amdgcn_mfma_f32_16x16x32_bf16(A0, B0, acc00, 0, 0, 0);
        acc01 = __builtin_amdgcn_mfma_f32_16x16x32_bf16(A0, B1, acc01, 0, 0, 0);
        acc10 = __builtin_amdgcn_mfma_f32_16x16x32_bf16(A1, B0, acc10, 0, 0, 0);
        acc11 = __builtin_amdgcn_mfma_f32_16x16x32_bf16(A1, B1, acc11, 0, 0, 0);
    }
    const float ba0 = ba[2 * w * 16 + col];
    const float ba1 = ba[(2 * w + 1) * 16 + col];
#pragma unroll
    for (int i = 0; i < 4; ++i) {
        const int r0 = grp * 4 + i;
        uls[r0][2 * w * 16 + col]            = (unsigned short)f2bf(fmaxf(acc00[i] + ba0, 0.f));
        uls[r0][(2 * w + 1) * 16 + col]      = (unsigned short)f2bf(fmaxf(acc01[i] + ba1, 0.f));
        uls[16 + r0][2 * w * 16 + col]       = (unsigned short)f2bf(fmaxf(acc10[i] + ba0, 0.f));
        uls[16 + r0][(2 * w + 1) * 16 + col] = (unsigned short)f2bf(fmaxf(acc11[i] + ba1, 0.f));
    }
    __syncthreads();

    acc00 = (f32x4){0,0,0,0}; acc01 = (f32x4){0,0,0,0};
    acc10 = (f32x4){0,0,0,0}; acc11 = (f32x4){0,0,0,0};
#pragma unroll
    for (int ks = 0; ks < 4; ++ks) {
        const short8v A0 = *(const short8v*)&uls[col][ks * 32 + grp * 8];
        const short8v A1 = *(const short8v*)&uls[16 + col][ks * 32 + grp * 8];
        const short8v B0 = *(const short8v*)&WbT[(size_t)(2 * w * 16 + col) * 128 + ks * 32 + grp * 8];
        const short8v B1 = *(const short8v*)&WbT[(size_t)((2 * w + 1) * 16 + col) * 128 + ks * 32 + grp * 8];
        acc00 = __builtin_amdgcn_mfma_f32_16x16x32_bf16(A0, B0, acc00, 0, 0, 0);
        acc01 = __builtin_amdgcn_mfma_f32_16x16x32_bf16(A0, B1, acc01, 0, 0, 0);
        acc10 = __builtin_amdgcn_mfma_f32_16x16x32_bf16(A1, B0, acc10, 0, 0, 0);
        acc11 = __builtin_amdgcn_mfma_f32_16x16x32_bf16(A1, B1, acc11, 0, 0, 0);
    }
    const float bb0 = bb[2 * w * 16 + col];
    const float bb1 = bb[(2 * w + 1) * 16 + col];

    if (MODE == 0) {
#pragma unroll
        for (int i = 0; i < 4; ++i) {
            const int nA = n0 + grp * 4 + i;
            if (nA < N_NODES) {
                const float v0 = fmaxf(acc00[i] + bb0, 0.f);
                const float v1 = fmaxf(acc01[i] + bb1, 0.f);
                *(unsigned int*)(h1out + (size_t)nA * 128 + 32 * w + 2 * col) =
                    (unsigned int)(unsigned short)f2bf(v0) |
                    ((unsigned int)(unsigned short)f2bf(v1) << 16);
            }
            const int nB = n0 + 16 + grp * 4 + i;
            if (nB < N_NODES) {
                const float v0 = fmaxf(acc10[i] + bb0, 0.f);
                const float v1 = fmaxf(acc11[i] + bb1, 0.f);
                *(unsigned int*)(h1out + (size_t)nB * 128 + 32 * w + 2 * col) =
                    (unsigned int)(unsigned short)f2bf(v0) |
                    ((unsigned int)(unsigned short)f2bf(v1) << 16);
            }
        }
    } else {
#pragma unroll
        for (int i = 0; i < 4; ++i) {
            const int r0 = grp * 4 + i;
            vls[r0][2 * w * 16 + col]            = fmaxf(acc00[i] + bb0, 0.f);
            vls[r0][(2 * w + 1) * 16 + col]      = fmaxf(acc01[i] + bb1, 0.f);
            vls[16 + r0][2 * w * 16 + col]       = fmaxf(acc10[i] + bb0, 0.f);
            vls[16 + r0][(2 * w + 1) * 16 + col] = fmaxf(acc11[i] + bb1, 0.f);
        }
        __syncthreads();
        if (tid < 128) {
            const int d = tid;
            const int lim = min(32, N_NODES - n0);
            float s = 0.0f;
            int bprev = -1;
            for (int q = 0; q < lim; ++q) {
                const int b = batch[n0 + q];
                if (b != bprev) {
                    if (bprev >= 0) atomicAdd(&pooled[bprev * 128 + d], s);
                    s = 0.0f;
                    bprev = b;
                }
                s += vls[q][d];
            }
            if (bprev >= 0) atomicAdd(&pooled[bprev * 128 + d], s);
        }
    }
}

// ---------------------------------------------------------------------------
// Final FC
// ---------------------------------------------------------------------------
__global__ __launch_bounds__(128) void fc_kernel(
    const float* __restrict__ pooled,
    const float* __restrict__ Wfc,
    const float* __restrict__ bfc,
    float* __restrict__ out)
{
    const int g = blockIdx.x;
    const int d = threadIdx.x;
    __shared__ float sp[128];
    sp[d] = pooled[g * 128 + d];
    __syncthreads();
    float acc = bfc[d];
    for (int k = 0; k < 128; ++k) acc = fmaf(sp[k], Wfc[k * 128 + d], acc);
    out[g * 128 + d] = acc;
}

extern "C" void kernel_launch(void* const* d_in, const int* in_sizes, int n_in,
                              void* d_out, int out_size, void* d_ws, size_t ws_size,
                              hipStream_t stream) {
    const float* x    = (const float*)d_in[0];
    const int*   eidx = (const int*)d_in[1];
    const float* ea   = (const float*)d_in[2];
    const int*   batch= (const int*)d_in[3];
    const float* We1  = (const float*)d_in[4];
    const float* be1  = (const float*)d_in[5];
    const float* W1a  = (const float*)d_in[6];
    const float* b1a  = (const float*)d_in[7];
    const float* W1b  = (const float*)d_in[8];
    const float* b1b  = (const float*)d_in[9];
    const float* We2  = (const float*)d_in[10];
    const float* be2  = (const float*)d_in[11];
    const float* W2a  = (const float*)d_in[12];
    const float* b2a  = (const float*)d_in[13];
    const float* W2b  = (const float*)d_in[14];
    const float* b2b  = (const float*)d_in[15];
    const float* Wfc  = (const float*)d_in[16];
    const float* bfc  = (const float*)d_in[17];
    float* out = (float*)d_out;

    const int* srcp = eidx;
    const int* dstp = eidx + N_EDGES;

    const int gblocks = 2048;
    const int mblocks = (N_NODES + 31) / 32;

    // workspace layout (53.8 MB, proven to fit)
    char* w = (char*)d_ws;
    unsigned short* bufA = (unsigned short*)w;  w += (size_t)N_NODES * 128 * 2;
    unsigned short* bufB = (unsigned short*)w;  w += (size_t)N_NODES * 128 * 2;
    int* deg   = (int*)w;                       w += (size_t)N_NODES * 4;
    int* basep = (int*)w;                       w += (size_t)N_NODES * 4;
    int* fillp = (int*)w;                       w += (size_t)N_NODES * 4;
    int* counter = (int*)w;                     w += 256;
    unsigned short* srcdst = (unsigned short*)w; w += (size_t)N_EDGES * 2;
    unsigned short* eadst = (unsigned short*)w;  w += (size_t)N_EDGES * 16 * 2;
    float* pooled = (float*)w;                  w += (size_t)N_GRAPHS * 128 * 4;
    unsigned short* W1aT = (unsigned short*)w;  w += (size_t)128 * 96 * 2;
    unsigned short* W1bT = (unsigned short*)w;  w += (size_t)128 * 128 * 2;
    unsigned short* W2aT = (unsigned short*)w;  w += (size_t)128 * 128 * 2;
    unsigned short* W2bT = (unsigned short*)w;  w += (size_t)128 * 128 * 2;

    // x16 lives in bufB (dead once mlp1 overwrites bufB with h1)
    unsigned short* x16 = bufB;

    // ---- prep: conversions (+zeroing) then compact CSR ----
    {
        const int total = T0_CVT + TW_CVT + 2 * N_NODES + 1;
        prep_convert<<<(total + 255) / 256, 256, 0, stream>>>(
            x, W1a, W1b, W2a, W2b, (unsigned int*)x16,
            W1aT, W1bT, W2aT, W2bT, deg, fillp, counter);
    }
    count_deg<<<(N_EDGES + 255) / 256, 256, 0, stream>>>(dstp, deg);
    assign_base<<<(N_NODES + 255) / 256, 256, 0, stream>>>(deg, basep, counter);
    scatter_edges<<<(N_EDGES + 255) / 256, 256, 0, stream>>>(
        dstp, srcp, ea, basep, fillp, srcdst, eadst);

    // ---- layer 1: x16(B) -> hpre(A); mlp1: A -> h1(B) ----
    gather_v9<96><<<gblocks, 256, 0, stream>>>(
        x16, srcdst, eadst, deg, basep, We1, be1, bufA, nullptr);
    mlp_mfma<96, 0><<<mblocks, 256, 0, stream>>>(
        bufA, W1aT, b1a, W1bT, b1b, bufB, nullptr, nullptr);

    // ---- layer 2: h1(B) -> hpre(A) (also zeroes pooled); mlp2: A -> pooled ----
    gather_v9<128><<<gblocks, 256, 0, stream>>>(
        bufB, srcdst, eadst, deg, basep, We2, be2, bufA, pooled);
    mlp_mfma<128, 1><<<mblocks, 256, 0, stream>>>(
        bufA, W2aT, b2a, W2bT, b2b, nullptr, batch, pooled);

    // ---- readout ----
    fc_kernel<<<N_GRAPHS, 128, 0, stream>>>(pooled, Wfc, bfc, out);
}

// Round 14
// 350.959 us; speedup vs baseline: 1.2360x; 1.2360x over previous
//
#include <hip/hip_runtime.h>
#include <hip/hip_bf16.h>

#define N_NODES 50000
#define N_EDGES 800000
#define N_GRAPHS 512

typedef __attribute__((ext_vector_type(8))) short short8v;   // 8 bf16
typedef __attribute__((ext_vector_type(4))) float f32x4;

__device__ inline float bf2f(unsigned short u) {
    union { unsigned int i; float f; } v; v.i = ((unsigned int)u) << 16; return v.f;
}
__device__ inline short f2bf(float f) {
    __hip_bfloat16 h = __float2bfloat16(f);
    return *reinterpret_cast<short*>(&h);
}

// ---------------------------------------------------------------------------
// PERMUTED bf16 row layout (row of D dims, D%32==0):
//   memory position m = 32*p + 2*c + half  <->  dim d = 32*p + 16*half + c
// uint i of a row = dims (32*(i>>4) + (i&15), 32*(i>>4) + 16 + (i&15))
// ---------------------------------------------------------------------------

// ======================= CSR prep =======================
__global__ __launch_bounds__(256) void count_deg(
    const int* __restrict__ dst, int* __restrict__ deg)
{
    int e = blockIdx.x * blockDim.x + threadIdx.x;
    if (e < N_EDGES) atomicAdd(&deg[dst[e]], 1);
}

__global__ __launch_bounds__(256) void assign_base(
    const int* __restrict__ deg, int* __restrict__ basep, int* __restrict__ counter)
{
    int n = blockIdx.x * blockDim.x + threadIdx.x;
    if (n < N_NODES) basep[n] = atomicAdd(counter, deg[n]);
}

// scatter edges into dst-contiguous stream: srcdst (ushort) + eadst (bf16 row)
__global__ __launch_bounds__(256) void scatter_edges(
    const int* __restrict__ dst, const int* __restrict__ src,
    const float* __restrict__ ea,
    const int* __restrict__ basep, int* __restrict__ fill,
    unsigned short* __restrict__ srcdst, unsigned short* __restrict__ eadst)
{
    int e = blockIdx.x * blockDim.x + threadIdx.x;
    if (e < N_EDGES) {
        const int d = dst[e];
        const int slot = atomicAdd(&fill[d], 1);
        const size_t pos = (size_t)basep[d] + slot;
        srcdst[pos] = (unsigned short)src[e];
        const float4* ap = (const float4*)(ea + (size_t)e * 16);
        const float4 a0 = ap[0], a1 = ap[1], a2 = ap[2], a3 = ap[3];
        short8v o0, o1;
        o0[0] = f2bf(a0.x); o0[1] = f2bf(a0.y); o0[2] = f2bf(a0.z); o0[3] = f2bf(a0.w);
        o0[4] = f2bf(a1.x); o0[5] = f2bf(a1.y); o0[6] = f2bf(a1.z); o0[7] = f2bf(a1.w);
        o1[0] = f2bf(a2.x); o1[1] = f2bf(a2.y); o1[2] = f2bf(a2.z); o1[3] = f2bf(a2.w);
        o1[4] = f2bf(a3.x); o1[5] = f2bf(a3.y); o1[6] = f2bf(a3.z); o1[7] = f2bf(a3.w);
        ((short8v*)eadst)[2 * pos]     = o0;
        ((short8v*)eadst)[2 * pos + 1] = o1;
    }
}

// ======================= merged conversions + zeroing (1 dispatch) =======================
// [0, T0): x fp32->permuted bf16 | W1aT | W1bT | W2aT | W2bT | deg=0 | fill=0 | counter=0
#define T0_CVT (N_NODES * 48)
#define TW_CVT (128 * 96 + 3 * 16384)
__global__ __launch_bounds__(256) void prep_convert(
    const float* __restrict__ x,
    const float* __restrict__ W1a, const float* __restrict__ W1b,
    const float* __restrict__ W2a, const float* __restrict__ W2b,
    unsigned int* __restrict__ x16,
    unsigned short* __restrict__ W1aT, unsigned short* __restrict__ W1bT,
    unsigned short* __restrict__ W2aT, unsigned short* __restrict__ W2bT,
    int* __restrict__ deg, int* __restrict__ fillp, int* __restrict__ counter)
{
    int t = blockIdx.x * blockDim.x + threadIdx.x;
    if (t < T0_CVT) {
        const int m2 = t % 48;
        const int n  = t / 48;
        const int p  = m2 >> 4;
        const int c  = m2 & 15;
        const float lo = x[(size_t)n * 96 + 32 * p + c];
        const float hi = x[(size_t)n * 96 + 32 * p + 16 + c];
        x16[t] = (unsigned int)(unsigned short)f2bf(lo) |
                 ((unsigned int)(unsigned short)f2bf(hi) << 16);
        return;
    }
    int u = t - T0_CVT;
    if (u < 128 * 96) { W1aT[u] = (unsigned short)f2bf(W1a[(u % 96) * 128 + u / 96]); return; }
    u -= 128 * 96;
    if (u < 16384) { W1bT[u] = (unsigned short)f2bf(W1b[(u & 127) * 128 + (u >> 7)]); return; }
    u -= 16384;
    if (u < 16384) { W2aT[u] = (unsigned short)f2bf(W2a[(u & 127) * 128 + (u >> 7)]); return; }
    u -= 16384;
    if (u < 16384) { W2bT[u] = (unsigned short)f2bf(W2b[(u & 127) * 128 + (u >> 7)]); return; }
    u -= 16384;
    if (u < N_NODES) { deg[u] = 0; return; }
    u -= N_NODES;
    if (u < N_NODES) { fillp[u] = 0; return; }
    u -= N_NODES;
    if (u == 0) { *counter = 0; }
}

// ======================= gather v7 (r10-proven: interleaved grid-stride) =======================
template <int DIN>
__global__ __launch_bounds__(256, 8) void gather_v7(
    const unsigned short* __restrict__ hin,    // [N,DIN] bf16 permuted
    const unsigned short* __restrict__ srcdst, // [E] ushort
    const unsigned short* __restrict__ eadst,  // [E][16] bf16, dst-contiguous
    const int* __restrict__ deg,
    const int* __restrict__ basep,
    const float* __restrict__ We,              // [16,DIN] fp32
    const float* __restrict__ be,              // [DIN]
    unsigned short* __restrict__ hpre,         // [N,DIN] bf16 permuted out
    float* __restrict__ pooled_zero)           // optional: zero before mlp2
{
    constexpr int NB = DIN / 16;
    constexpr int NP = DIN / 32;

    // fold pooled zeroing into this dispatch (runs strictly before mlp MODE 1)
    if (pooled_zero) {
        const int t = blockIdx.x * blockDim.x + threadIdx.x;
        if (t < N_GRAPHS * 128 / 4) {
            ((float4*)pooled_zero)[t] = make_float4(0.f, 0.f, 0.f, 0.f);
        }
    }

    const int lane = threadIdx.x & 63;
    const int col = lane & 15;
    const int grp = lane >> 4;
    const int gwave = (blockIdx.x * blockDim.x + threadIdx.x) >> 6;
    const int nwaves = (gridDim.x * blockDim.x) >> 6;

    // B fragments: We rows k=grp*8+j (grp<2); bias row at k=16 (grp2, j=0)
    short8v Bf[NB];
#pragma unroll
    for (int b = 0; b < NB; ++b) {
        short8v f = {};
        if (grp < 2) {
#pragma unroll
            for (int j = 0; j < 8; ++j)
                f[j] = f2bf(We[(grp * 8 + j) * DIN + b * 16 + col]);
        } else if (grp == 2) {
            f[0] = f2bf(be[b * 16 + col]);
        }
        Bf[b] = f;
    }

    // INTERLEAVED grid-stride: concurrent waves form a contiguous sweeping
    // node window -> eadst/srcdst reads stay in a small sliding L2 region.
    // (r13 lesson: contiguous per-wave ranges scatter the working set, +188MB)
    for (int n = gwave; n < N_NODES; n += nwaves) {
        const int dgc = deg[n];
        const int nch = (dgc + 15) >> 4;
        const int b0 = basep[n];

        float accv[NB];
#pragma unroll
        for (int b = 0; b < NB; ++b) accv[b] = 0.0f;

        for (int c = 0; c < nch; ++c) {
            const int pos0 = b0 + 16 * c;
            const int vcc = min(dgc - 16 * c, 16);   // valid edges (1..16)

            // lanes 0..vcc-1: src id (2B each, contiguous)
            int s_l = 0;
            if (lane < vcc) s_l = srcdst[pos0 + lane];

            // A fragment: lane col's edge row, SEQUENTIAL 32B records
            short8v Af = {};
            if (grp < 2) {
                if (col < vcc)
                    Af = *(const short8v*)(eadst + (size_t)(pos0 + col) * 16 + grp * 8);
            } else if (grp == 2) {
                Af[0] = (short)0x3F80;   // bf16 1.0 -> bias row
            }

            // src ids for this lane's 4 output rows (edges 4*grp+r)
            int sid[4];
#pragma unroll
            for (int r = 0; r < 4; ++r) sid[r] = __shfl(s_l, 4 * grp + r);

#pragma unroll
            for (int p = 0; p < NP; ++p) {
                const f32x4 zero = {0.0f, 0.0f, 0.0f, 0.0f};
                f32x4 lin0 = __builtin_amdgcn_mfma_f32_16x16x32_bf16(Af, Bf[2 * p], zero, 0, 0, 0);
                f32x4 lin1 = __builtin_amdgcn_mfma_f32_16x16x32_bf16(Af, Bf[2 * p + 1], zero, 0, 0, 0);
                float part0 = 0.0f, part1 = 0.0f;
#pragma unroll
                for (int r = 0; r < 4; ++r) {
                    if (4 * grp + r < vcc) {
                        const unsigned int u = *(const unsigned int*)
                            (hin + (size_t)sid[r] * DIN + 32 * p + 2 * col);
                        const float xlo = bf2f((unsigned short)(u & 0xffffu));
                        const float xhi = bf2f((unsigned short)(u >> 16));
                        part0 += fmaxf(xlo + lin0[r], 0.0f);
                        part1 += fmaxf(xhi + lin1[r], 0.0f);
                    }
                }
                accv[2 * p]     += part0;   // deferred cross-lane reduce
                accv[2 * p + 1] += part1;
            }
        }

        // reduce across lane groups once per node
#pragma unroll
        for (int b = 0; b < NB; ++b) {
            accv[b] += __shfl_xor(accv[b], 16);
            accv[b] += __shfl_xor(accv[b], 32);
        }

        // self term + store (fused h = x + agg), permuted bf16 out
        if (lane < 16) {
#pragma unroll
            for (int p = 0; p < NP; ++p) {
                const unsigned int u = *(const unsigned int*)
                    (hin + (size_t)n * DIN + 32 * p + 2 * lane);
                const float lo = bf2f((unsigned short)(u & 0xffffu)) + accv[2 * p];
                const float hi = bf2f((unsigned short)(u >> 16)) + accv[2 * p + 1];
                *(unsigned int*)(hpre + (size_t)n * DIN + 32 * p + 2 * lane) =
                    (unsigned int)(unsigned short)f2bf(lo) |
                    ((unsigned int)(unsigned short)f2bf(hi) << 16);
            }
        }
    }
}

// ======================= MFMA GIN MLP (proven) =======================
template <int DIN, int MODE>
__global__ __launch_bounds__(256) void mlp_mfma(
    const unsigned short* __restrict__ hpre,  // [N,DIN] bf16 permuted
    const unsigned short* __restrict__ WaT,   // [128][DIN] bf16
    const float* __restrict__ ba,
    const unsigned short* __restrict__ WbT,   // [128][128] bf16
    const float* __restrict__ bb,
    unsigned short* __restrict__ h1out,       // MODE 0 (permuted)
    const int* __restrict__ batch,            // MODE 1
    float* __restrict__ pooled)               // MODE 1 (pre-zeroed)
{
    constexpr int KS1 = DIN / 32;
    __shared__ unsigned short hls[32][DIN + 8];
    __shared__ unsigned short uls[32][128 + 8];
    __shared__ float vls[(MODE == 1) ? 32 : 1][(MODE == 1) ? 132 : 1];

    const int n0 = blockIdx.x * 32;
    const int tid = threadIdx.x;

    for (int f = tid * 4; f < 32 * DIN; f += 1024) {
        const int row = f / DIN, colc = f % DIN;
        const int n = n0 + row;
        ushort4 u = make_ushort4(0, 0, 0, 0);
        if (n < N_NODES) u = *(const ushort4*)(hpre + (size_t)n * DIN + colc);
        const int p = colc >> 5;
        const int q = (colc & 31) >> 2;
        hls[row][32 * p + 2 * q]          = u.x;
        hls[row][32 * p + 16 + 2 * q]     = u.y;
        hls[row][32 * p + 2 * q + 1]      = u.z;
        hls[row][32 * p + 16 + 2 * q + 1] = u.w;
    }
    __syncthreads();

    const int lane = tid & 63;
    const int w = tid >> 6;
    const int col = lane & 15;
    const int grp = lane >> 4;

    f32x4 acc00 = {0,0,0,0}, acc01 = {0,0,0,0}, acc10 = {0,0,0,0}, acc11 = {0,0,0,0};
#pragma unroll
    for (int ks = 0; ks < KS1; ++ks) {
        const short8v A0 = *(const short8v*)&hls[col][ks * 32 + grp * 8];
        const short8v A1 = *(const short8v*)&hls[16 + col][ks * 32 + grp * 8];
        const short8v B0 = *(const short8v*)&WaT[(size_t)(2 * w * 16 + col) * DIN + ks * 32 + grp * 8];
        const short8v B1 = *(const short8v*)&WaT[(size_t)((2 * w + 1) * 16 + col) * DIN + ks * 32 + grp * 8];
        acc00 = __builtin_amdgcn_mfma_f32_16x16x32_bf16(A0, B0, acc00, 0, 0, 0);
        acc01 = __builtin_amdgcn_mfma_f32_16x16x32_bf16(A0, B1, acc01, 0, 0, 0);
        acc10 = __builtin_amdgcn_mfma_f32_16x16x32_bf16(A1, B0, acc10, 0, 0, 0);
        acc11 = __builtin_amdgcn_mfma_f32_16x16x32_bf16(A1, B1, acc11, 0, 0, 0);
    }
    const float ba0 = ba[2 * w * 16 + col];
    const float ba1 = ba[(2 * w + 1) * 16 + col];
#pragma unroll
    for (int i = 0; i < 4; ++i) {
        const int r0 = grp * 4 + i;
        uls[r0][2 * w * 16 + col]            = (unsigned short)f2bf(fmaxf(acc00[i] + ba0, 0.f));
        uls[r0][(2 * w + 1) * 16 + col]      = (unsigned short)f2bf(fmaxf(acc01[i] + ba1, 0.f));
        uls[16 + r0][2 * w * 16 + col]       = (unsigned short)f2bf(fmaxf(acc10[i] + ba0, 0.f));
        uls[16 + r0][(2 * w + 1) * 16 + col] = (unsigned short)f2bf(fmaxf(acc11[i] + ba1, 0.f));
    }
    __syncthreads();

    acc00 = (f32x4){0,0,0,0}; acc01 = (f32x4){0,0,0,0};
    acc10 = (f32x4){0,0,0,0}; acc11 = (f32x4){0,0,0,0};
#pragma unroll
    for (int ks = 0; ks < 4; ++ks) {
        const short8v A0 = *(const short8v*)&uls[col][ks * 32 + grp * 8];
        const short8v A1 = *(const short8v*)&uls[16 + col][ks * 32 + grp * 8];
        const short8v B0 = *(const short8v*)&WbT[(size_t)(2 * w * 16 + col) * 128 + ks * 32 + grp * 8];
        const short8v B1 = *(const short8v*)&WbT[(size_t)((2 * w + 1) * 16 + col) * 128 + ks * 32 + grp * 8];
        acc00 = __builtin_amdgcn_mfma_f32_16x16x32_bf16(A0, B0, acc00, 0, 0, 0);
        acc01 = __builtin_amdgcn_mfma_f32_16x16x32_bf16(A0, B1, acc01, 0, 0, 0);
        acc10 = __builtin_amdgcn_mfma_f32_16x16x32_bf16(A1, B0, acc10, 0, 0, 0);
        acc11 = __builtin_amdgcn_mfma_f32_16x16x32_bf16(A1, B1, acc11, 0, 0, 0);
    }
    const float bb0 = bb[2 * w * 16 + col];
    const float bb1 = bb[(2 * w + 1) * 16 + col];

    if (MODE == 0) {
#pragma unroll
        for (int i = 0; i < 4; ++i) {
            const int nA = n0 + grp * 4 + i;
            if (nA < N_NODES) {
                const float v0 = fmaxf(acc00[i] + bb0, 0.f);
                const float v1 = fmaxf(acc01[i] + bb1, 0.f);
                *(unsigned int*)(h1out + (size_t)nA * 128 + 32 * w + 2 * col) =
                    (unsigned int)(unsigned short)f2bf(v0) |
                    ((unsigned int)(unsigned short)f2bf(v1) << 16);
            }
            const int nB = n0 + 16 + grp * 4 + i;
            if (nB < N_NODES) {
                const float v0 = fmaxf(acc10[i] + bb0, 0.f);
                const float v1 = fmaxf(acc11[i] + bb1, 0.f);
                *(unsigned int*)(h1out + (size_t)nB * 128 + 32 * w + 2 * col) =
                    (unsigned int)(unsigned short)f2bf(v0) |
                    ((unsigned int)(unsigned short)f2bf(v1) << 16);
            }
        }
    } else {
#pragma unroll
        for (int i = 0; i < 4; ++i) {
            const int r0 = grp * 4 + i;
            vls[r0][2 * w * 16 + col]            = fmaxf(acc00[i] + bb0, 0.f);
            vls[r0][(2 * w + 1) * 16 + col]      = fmaxf(acc01[i] + bb1, 0.f);
            vls[16 + r0][2 * w * 16 + col]       = fmaxf(acc10[i] + bb0, 0.f);
            vls[16 + r0][(2 * w + 1) * 16 + col] = fmaxf(acc11[i] + bb1, 0.f);
        }
        __syncthreads();
        if (tid < 128) {
            const int d = tid;
            const int lim = min(32, N_NODES - n0);
            float s = 0.0f;
            int bprev = -1;
            for (int q = 0; q < lim; ++q) {
                const int b = batch[n0 + q];
                if (b != bprev) {
                    if (bprev >= 0) atomicAdd(&pooled[bprev * 128 + d], s);
                    s = 0.0f;
                    bprev = b;
                }
                s += vls[q][d];
            }
            if (bprev >= 0) atomicAdd(&pooled[bprev * 128 + d], s);
        }
    }
}

// ---------------------------------------------------------------------------
// Final FC
// ---------------------------------------------------------------------------
__global__ __launch_bounds__(128) void fc_kernel(
    const float* __restrict__ pooled,
    const float* __restrict__ Wfc,
    const float* __restrict__ bfc,
    float* __restrict__ out)
{
    const int g = blockIdx.x;
    const int d = threadIdx.x;
    __shared__ float sp[128];
    sp[d] = pooled[g * 128 + d];
    __syncthreads();
    float acc = bfc[d];
    for (int k = 0; k < 128; ++k) acc = fmaf(sp[k], Wfc[k * 128 + d], acc);
    out[g * 128 + d] = acc;
}

extern "C" void kernel_launch(void* const* d_in, const int* in_sizes, int n_in,
                              void* d_out, int out_size, void* d_ws, size_t ws_size,
                              hipStream_t stream) {
    const float* x    = (const float*)d_in[0];
    const int*   eidx = (const int*)d_in[1];
    const float* ea   = (const float*)d_in[2];
    const int*   batch= (const int*)d_in[3];
    const float* We1  = (const float*)d_in[4];
    const float* be1  = (const float*)d_in[5];
    const float* W1a  = (const float*)d_in[6];
    const float* b1a  = (const float*)d_in[7];
    const float* W1b  = (const float*)d_in[8];
    const float* b1b  = (const float*)d_in[9];
    const float* We2  = (const float*)d_in[10];
    const float* be2  = (const float*)d_in[11];
    const float* W2a  = (const float*)d_in[12];
    const float* b2a  = (const float*)d_in[13];
    const float* W2b  = (const float*)d_in[14];
    const float* b2b  = (const float*)d_in[15];
    const float* Wfc  = (const float*)d_in[16];
    const float* bfc  = (const float*)d_in[17];
    float* out = (float*)d_out;

    const int* srcp = eidx;
    const int* dstp = eidx + N_EDGES;

    const int gblocks = 2048;
    const int mblocks = (N_NODES + 31) / 32;

    // workspace layout (53.8 MB, proven to fit)
    char* w = (char*)d_ws;
    unsigned short* bufA = (unsigned short*)w;  w += (size_t)N_NODES * 128 * 2;
    unsigned short* bufB = (unsigned short*)w;  w += (size_t)N_NODES * 128 * 2;
    int* deg   = (int*)w;                       w += (size_t)N_NODES * 4;
    int* basep = (int*)w;                       w += (size_t)N_NODES * 4;
    int* fillp = (int*)w;                       w += (size_t)N_NODES * 4;
    int* counter = (int*)w;                     w += 256;
    unsigned short* srcdst = (unsigned short*)w; w += (size_t)N_EDGES * 2;
    unsigned short* eadst = (unsigned short*)w;  w += (size_t)N_EDGES * 16 * 2;
    float* pooled = (float*)w;                  w += (size_t)N_GRAPHS * 128 * 4;
    unsigned short* W1aT = (unsigned short*)w;  w += (size_t)128 * 96 * 2;
    unsigned short* W1bT = (unsigned short*)w;  w += (size_t)128 * 128 * 2;
    unsigned short* W2aT = (unsigned short*)w;  w += (size_t)128 * 128 * 2;
    unsigned short* W2bT = (unsigned short*)w;  w += (size_t)128 * 128 * 2;

    // x16 lives in bufB (dead once mlp1 overwrites bufB with h1)
    unsigned short* x16 = bufB;

    // ---- prep: conversions (+zeroing) then compact CSR ----
    {
        const int total = T0_CVT + TW_CVT + 2 * N_NODES + 1;
        prep_convert<<<(total + 255) / 256, 256, 0, stream>>>(
            x, W1a, W1b, W2a, W2b, (unsigned int*)x16,
            W1aT, W1bT, W2aT, W2bT, deg, fillp, counter);
    }
    count_deg<<<(N_EDGES + 255) / 256, 256, 0, stream>>>(dstp, deg);
    assign_base<<<(N_NODES + 255) / 256, 256, 0, stream>>>(deg, basep, counter);
    scatter_edges<<<(N_EDGES + 255) / 256, 256, 0, stream>>>(
        dstp, srcp, ea, basep, fillp, srcdst, eadst);

    // ---- layer 1: x16(B) -> hpre(A); mlp1: A -> h1(B) ----
    gather_v7<96><<<gblocks, 256, 0, stream>>>(
        x16, srcdst, eadst, deg, basep, We1, be1, bufA, nullptr);
    mlp_mfma<96, 0><<<mblocks, 256, 0, stream>>>(
        bufA, W1aT, b1a, W1bT, b1b, bufB, nullptr, nullptr);

    // ---- layer 2: h1(B) -> hpre(A) (also zeroes pooled); mlp2: A -> pooled ----
    gather_v7<128><<<gblocks, 256, 0, stream>>>(
        bufB, srcdst, eadst, deg, basep, We2, be2, bufA, pooled);
    mlp_mfma<128, 1><<<mblocks, 256, 0, stream>>>(
        bufA, W2aT, b2a, W2bT, b2b, nullptr, batch, pooled);

    // ---- readout ----
    fc_kernel<<<N_GRAPHS, 128, 0, stream>>>(pooled, Wfc, bfc, out);
}